// Round 1
// baseline (354.082 us; speedup 1.0000x reference)
//
#include <hip/hip_runtime.h>
#include <cstdint>
#include <type_traits>

typedef unsigned short u16;
typedef _Float16 f16;
typedef __attribute__((ext_vector_type(8))) short    s8v;  // 8 bf16 (4 VGPRs)
typedef __attribute__((ext_vector_type(8))) _Float16 h8v;  // 8 fp16 (4 VGPRs)
typedef __attribute__((ext_vector_type(4))) float    f4v;

__device__ __forceinline__ float bf2f(u16 b) {
  unsigned int u = ((unsigned int)b) << 16;
  float f;
  __builtin_memcpy(&f, &u, 4);
  return f;
}
__device__ __forceinline__ u16 f2bf(float f) {
  unsigned int u;
  __builtin_memcpy(&u, &f, 4);
  u += 0x7fffu + ((u >> 16) & 1u);   // RNE (finite inputs only)
  return (u16)(u >> 16);
}

// async global->LDS, 16B per lane; LDS dest = wave-uniform base + lane*16
__device__ __forceinline__ void glds16(const void* g, void* l) {
  __builtin_amdgcn_global_load_lds(
      (const __attribute__((address_space(1))) unsigned int*)g,
      (__attribute__((address_space(3))) unsigned int*)l, 16, 0, 0);
}

// XCD-aware swizzle (bijective whenever gx*gy % 8 == 0 — all grids here qualify)
__device__ __forceinline__ void swz_xy(int& bx, int& by) {
  const int gx = gridDim.x;
  const int p = blockIdx.y * gx + blockIdx.x;
  bx = (p >> 3) % gx;
  by = (p & 7) + 8 * (p / (gx * 8));
}

// =====================================================================
// Ring-4 counted-vmcnt GEMM pipeline (T3+T4+T5).
//   - one step = one K=32 sub-tile; slot = s & 3
//   - step s issues async stages for sub-tile s+2 into slot (s+2)&3
//   - end of step: s_waitcnt vmcnt(NST) retires sub-tile s+1's batch
//     (never 0 in steady state -> loads stay in flight across barriers)
//   - raw s_barrier (NOT __syncthreads, which would drain vmcnt(0))
//   - slot safety: last read of a slot is >= 2 barriers before its rewrite;
//     ds_reads are lgkm-drained before the MFMA cluster by the compiler.
// LDS layout per slot: A [256][32] fp16-ish at 0, B [BN][32] at u16 8192,
// rows of 64B with chunk-XOR swizzle (write chunk = c ^ ((row>>1)&3)).
// =====================================================================
template<bool BF, int MI, int NB, int SLOTU>
__device__ __forceinline__ void pipeK(u16* Ls,
    const u16* ga0, const u16* ga1, const u16* gb0, const u16* gb1,
    const int stA, const int stB, const int aoff, const int boff,
    const int nSub, f4v (&acc)[MI][4])
{
  using FV = typename std::conditional<BF, s8v, h8v>::type;
  auto stage = [&](int st) {
    glds16(ga0, Ls + st + stA);
    glds16(ga1, Ls + st + stA + 512);
    glds16(gb0, Ls + st + stB);
    if constexpr (NB == 2) { glds16(gb1, Ls + st + stB + 512); gb1 += 32; }
    ga0 += 32; ga1 += 32; gb0 += 32;
  };
  // prologue: sub-tiles 0 and 1; retire batch 0 only (batch 1 stays in flight)
  stage(0);
  stage(SLOTU);
  if constexpr (NB == 2) asm volatile("s_waitcnt vmcnt(4)" ::: "memory");
  else                   asm volatile("s_waitcnt vmcnt(3)" ::: "memory");
  __builtin_amdgcn_s_barrier();

  for (int s = 0; s < nSub; ++s) {
    const int sl = (s & 3) * SLOTU;
    FV af[MI], bv[4];
#pragma unroll
    for (int mi = 0; mi < MI; ++mi) af[mi] = *(const FV*)&Ls[sl + aoff + mi * 512];
#pragma unroll
    for (int ni = 0; ni < 4; ++ni)  bv[ni] = *(const FV*)&Ls[sl + boff + ni * 512];
    const bool more = (s + 2 < nSub);
    if (more) stage(((s + 2) & 3) * SLOTU);
    __builtin_amdgcn_s_setprio(1);
#pragma unroll
    for (int mi = 0; mi < MI; ++mi)
#pragma unroll
      for (int ni = 0; ni < 4; ++ni) {
        if constexpr (BF)
          acc[mi][ni] = __builtin_amdgcn_mfma_f32_16x16x32_bf16(af[mi], bv[ni], acc[mi][ni], 0, 0, 0);
        else
          acc[mi][ni] = __builtin_amdgcn_mfma_f32_16x16x32_f16(af[mi], bv[ni], acc[mi][ni], 0, 0, 0);
      }
    __builtin_amdgcn_s_setprio(0);
    if (more) {
      if constexpr (NB == 2) asm volatile("s_waitcnt vmcnt(4)" ::: "memory");
      else                   asm volatile("s_waitcnt vmcnt(3)" ::: "memory");
    } else {
      // tail: only one (or zero) batch outstanding -> must drain fully
      asm volatile("s_waitcnt vmcnt(0)" ::: "memory");
    }
    __builtin_amdgcn_s_barrier();
  }
}

// ---------------- dtype detector (flg[0]=1: fp32 storage, 0: bf16) ----------------
__global__ __launch_bounds__(256)
void detect_dtype(const u16* __restrict__ q, int* __restrict__ flg)
{
  __shared__ int cbig, czero;
  if (threadIdx.x == 0) { cbig = 0; czero = 0; }
  __syncthreads();
  int b = 0, z = 0;
  for (int i = threadIdx.x; i < 4096; i += 256) {
    float v = bf2f(q[i]);
    if (!(fabsf(v) < 1e4f)) b++;
    if ((i & 1) == 0 && q[i] == 0) z++;
  }
  atomicAdd(&cbig, b);
  atomicAdd(&czero, z);
  __syncthreads();
  if (threadIdx.x == 0) flg[0] = (cbig > 64 || czero > 1600) ? 1 : 0;
}

// ---------------- inputs -> fp16 plane (query & kv in one launch) ----------------
__global__ __launch_bounds__(256)
void convert_h(const int* __restrict__ flg,
               const void* __restrict__ q, const void* __restrict__ kv,
               f16* __restrict__ qo, f16* __restrict__ kvo, long n)
{
  const void* in = blockIdx.y ? kv : q;
  f16* out = blockIdx.y ? kvo : qo;
  const long i = ((long)blockIdx.x * 256 + threadIdx.x) * 8;
  if (i >= n) return;
  h8v h;
  if (flg[0] != 0) {
    const float* p = (const float*)in + i;
    f4v f0 = *(const f4v*)p;
    f4v f1 = *(const f4v*)(p + 4);
#pragma unroll
    for (int j = 0; j < 4; ++j) {
      h[j]     = (f16)f0[j];
      h[4 + j] = (f16)f1[j];
    }
  } else {
    s8v b = *(const s8v*)((const short*)in + i);
#pragma unroll
    for (int j = 0; j < 8; ++j) h[j] = (f16)bf2f((u16)b[j]);
  }
  *(h8v*)(out + i) = h;
}

// ---------------- four W^T in one launch: z<3 -> fp16 (Wq,Wk,Wv); z=3 -> bf16 (Wo) ----
__global__ __launch_bounds__(256)
void transpose_w4(const int* __restrict__ flg,
                  const void* __restrict__ w0, const void* __restrict__ w1,
                  const void* __restrict__ w2, const void* __restrict__ w3,
                  f16* __restrict__ h0, f16* __restrict__ h1,
                  f16* __restrict__ h2, u16* __restrict__ b3, int D)
{
  __shared__ float tile[32][33];
  const int zb = blockIdx.z;
  const void* in_v = (zb == 0) ? w0 : (zb == 1) ? w1 : (zb == 2) ? w2 : w3;
  const bool i32 = (flg[0] != 0);
  const u16*   in16 = (const u16*)in_v;
  const float* in32 = (const float*)in_v;
  const int c0 = blockIdx.x * 32, r0 = blockIdx.y * 32;
  const int tx = threadIdx.x, ty = threadIdx.y;   // block (32,8)
  for (int i = ty; i < 32; i += 8) {
    const long idx = (long)(r0 + i) * D + c0 + tx;
    tile[i][tx] = i32 ? in32[idx] : bf2f(in16[idx]);
  }
  __syncthreads();
  f16* outH = (zb == 0) ? h0 : (zb == 1) ? h1 : h2;
  for (int i = ty; i < 32; i += 8) {
    const long idx = (long)(c0 + i) * D + r0 + tx;
    const float v = tile[tx][i];
    if (zb == 3) b3[idx]   = f2bf(v);
    else         outH[idx] = (f16)v;
  }
}

// ---------------- Q/K/V projections: 256^2 tile, 8 waves (2x4), ring-4 pipeline ----
__global__ __launch_bounds__(512)
void gemm_proj3(const int* __restrict__ flg,
                const f16* __restrict__ Qi, const f16* __restrict__ KVi,
                const f16* __restrict__ WqT, const f16* __restrict__ WkT,
                const f16* __restrict__ WvT,
                const void* __restrict__ bq, const void* __restrict__ bk,
                const void* __restrict__ bv,
                f16* __restrict__ Qf, f16* __restrict__ Kf,
                u16* __restrict__ Vt, int M, int N, int K, int SB)
{
  __shared__ u16 Ls[65536];          // 128 KB: 4 ring slots x (A 16KB + B 16KB)
  const int zb = blockIdx.z;
  const u16* A = (const u16*)((zb == 0) ? Qi : KVi);
  const u16* B = (const u16*)((zb == 0) ? WqT : (zb == 1) ? WkT : WvT);
  const void* bias = (zb == 0) ? bq : (zb == 1) ? bk : bv;
  int f_in = flg[0];
  asm volatile("" : "+v"(f_in));     // retire flag load now (vmcnt discipline)

  const int tid = threadIdx.x, lane = tid & 63, wave = tid >> 6;
  const int wm = wave >> 2, wn = wave & 3;             // 2 x 4 wave grid
  int bx, by; swz_xy(bx, by);
  const int m0 = by * 256, n0 = bx * 256;

  const int rr  = wave * 32 + (lane >> 2);             // staging row (8w x 32r = 256)
  const int cc8 = 8 * ((lane & 3) ^ ((lane >> 3) & 3));
  const u16* ga0 = A + (long)(m0 + rr) * K + cc8;
  const u16* ga1 = ga0 + 16 * (long)K;
  const u16* gb0 = B + (long)(n0 + rr) * K + cc8;
  const u16* gb1 = gb0 + 16 * (long)K;
  const int stA = wave * 1024, stB = 8192 + wave * 1024;

  const int fr  = lane & 15;
  const int fks = 8 * (((lane >> 4) ^ (lane >> 1)) & 3);
  const int aoff = (wm * 128 + fr) * 32 + fks;
  const int boff = 8192 + (wn * 64 + fr) * 32 + fks;

  f4v acc[8][4];
#pragma unroll
  for (int i = 0; i < 8; ++i)
#pragma unroll
    for (int j = 0; j < 4; ++j) acc[i][j] = (f4v){0.f, 0.f, 0.f, 0.f};

  pipeK<false, 8, 2, 16384>(Ls, ga0, ga1, gb0, gb1, stA, stB, aoff, boff, K >> 5, acc);

  const int cr = (lane >> 4) * 4, ccl = lane & 15;
  if (zb < 2) {
    f16* out = zb ? Kf : Qf;
#pragma unroll
    for (int ni = 0; ni < 4; ++ni) {
      const int gcol = n0 + wn * 64 + ni * 16 + ccl;
      const float bvv = (f_in != 0) ? ((const float*)bias)[gcol]
                                    : bf2f(((const u16*)bias)[gcol]);
#pragma unroll
      for (int mi = 0; mi < 8; ++mi)
#pragma unroll
        for (int r = 0; r < 4; ++r) {
          const long grow = (long)(m0 + wm * 128 + mi * 16 + cr + r);
          out[grow * N + gcol] = (f16)(acc[mi][ni][r] + bvv);
        }
    }
  } else {
    // V: transposed bf16 epilogue through dead staging LDS (per-wave 2176 u16)
    u16* xw = &Ls[wave * 2176];
    const int b   = m0 / SB;
    const int s0w = (m0 % SB) + wm * 128;
    const long bbase = (long)b * (long)N * SB;
    __syncthreads();
#pragma unroll
    for (int sh = 0; sh < 2; ++sh) {
#pragma unroll
      for (int dh = 0; dh < 2; ++dh) {
#pragma unroll
        for (int nl = 0; nl < 2; ++nl) {
          const int ni = dh * 2 + nl;
          const int gcol = n0 + wn * 64 + ni * 16 + ccl;
          const float bvv = (f_in != 0) ? ((const float*)bias)[gcol]
                                        : bf2f(((const u16*)bias)[gcol]);
#pragma unroll
          for (int ml = 0; ml < 4; ++ml)
#pragma unroll
            for (int r = 0; r < 4; ++r)
              xw[(ml * 16 + cr + r) * 34 + nl * 16 + ccl] =
                  f2bf(acc[sh * 4 + ml][ni][r] + bvv);
        }
        __syncthreads();
#pragma unroll
        for (int c = 0; c < 32; ++c) {
          const int gd = n0 + wn * 64 + dh * 32 + c;
          Vt[bbase + (long)gd * SB + s0w + sh * 64 + lane] = xw[lane * 34 + c];
        }
        __syncthreads();
      }
    }
  }
}

// ---------------- scores GEMM: 256^2 tile, fp16, fp32 out, z-batched ----------------
__global__ __launch_bounds__(512)
void gemm_sc(const f16* __restrict__ A_, const f16* __restrict__ B_,
             float* __restrict__ C, int M, int N, int K,
             long sA, long sB, long sC)
{
  __shared__ u16 Ls[65536];
  const long z = blockIdx.z;
  const u16* A = (const u16*)A_ + z * sA;
  const u16* B = (const u16*)B_ + z * sB;

  const int tid = threadIdx.x, lane = tid & 63, wave = tid >> 6;
  const int wm = wave >> 2, wn = wave & 3;
  int bx, by; swz_xy(bx, by);
  const int m0 = by * 256, n0 = bx * 256;

  const int rr  = wave * 32 + (lane >> 2);
  const int cc8 = 8 * ((lane & 3) ^ ((lane >> 3) & 3));
  const u16* ga0 = A + (long)(m0 + rr) * K + cc8;
  const u16* ga1 = ga0 + 16 * (long)K;
  const u16* gb0 = B + (long)(n0 + rr) * K + cc8;
  const u16* gb1 = gb0 + 16 * (long)K;
  const int stA = wave * 1024, stB = 8192 + wave * 1024;

  const int fr  = lane & 15;
  const int fks = 8 * (((lane >> 4) ^ (lane >> 1)) & 3);
  const int aoff = (wm * 128 + fr) * 32 + fks;
  const int boff = 8192 + (wn * 64 + fr) * 32 + fks;

  f4v acc[8][4];
#pragma unroll
  for (int i = 0; i < 8; ++i)
#pragma unroll
    for (int j = 0; j < 4; ++j) acc[i][j] = (f4v){0.f, 0.f, 0.f, 0.f};

  pipeK<false, 8, 2, 16384>(Ls, ga0, ga1, gb0, gb1, stA, stB, aoff, boff, K >> 5, acc);

  const int cr = (lane >> 4) * 4, ccl = lane & 15;
  float* Cz = C + z * sC;
#pragma unroll
  for (int ni = 0; ni < 4; ++ni) {
    const int gcol = n0 + wn * 64 + ni * 16 + ccl;
#pragma unroll
    for (int mi = 0; mi < 8; ++mi)
#pragma unroll
      for (int r = 0; r < 4; ++r)
        Cz[(long)(m0 + wm * 128 + mi * 16 + cr + r) * N + gcol] = acc[mi][ni][r];
  }
}

// ---------------- bf16 NT GEMM: 256x128 tile, 8 waves (4x2), ring-4 (PV, out-proj) ----
// 256x128 keeps the grid at 256 blocks (full CU round) for N=1024 shapes.
template<bool OUT_FLAG, bool HAS_BIAS>
__global__ __launch_bounds__(512)
void gemm_bf(const int* __restrict__ flg, const u16* __restrict__ A_,
             const u16* __restrict__ Bt, const void* __restrict__ bias,
             void* __restrict__ Cv, int M, int N, int K,
             long sA, long sB, long sC)
{
  __shared__ u16 Ls[49152];          // 96 KB: 4 slots x (A 16KB + B 8KB)
  int f_in = flg[0];
  asm volatile("" : "+v"(f_in));

  const int tid = threadIdx.x, lane = tid & 63, wave = tid >> 6;
  const int wm = wave >> 1, wn = wave & 1;             // 4 x 2 wave grid
  int bx, by; swz_xy(bx, by);
  const int m0 = by * 256, n0 = bx * 128;
  const long z = blockIdx.z;
  const u16* A = A_ + z * sA;
  const u16* B = Bt + z * sB;

  const int rr  = wave * 32 + (lane >> 2);
  const int cc8 = 8 * ((lane & 3) ^ ((lane >> 3) & 3));
  const u16* ga0 = A + (long)(m0 + rr) * K + cc8;
  const u16* ga1 = ga0 + 16 * (long)K;
  const u16* gb0 = B + (long)(n0 + wave * 16 + (lane >> 2)) * K + cc8;  // 16 rows/wave
  const int stA = wave * 1024, stB = 8192 + wave * 512;

  const int fr  = lane & 15;
  const int fks = 8 * (((lane >> 4) ^ (lane >> 1)) & 3);
  const int aoff = (wm * 64 + fr) * 32 + fks;
  const int boff = 8192 + (wn * 64 + fr) * 32 + fks;

  f4v acc[4][4];
#pragma unroll
  for (int i = 0; i < 4; ++i)
#pragma unroll
    for (int j = 0; j < 4; ++j) acc[i][j] = (f4v){0.f, 0.f, 0.f, 0.f};

  pipeK<true, 4, 1, 12288>(Ls, ga0, ga1, gb0, gb0, stA, stB, aoff, boff, K >> 5, acc);

  const int cr = (lane >> 4) * 4, ccl = lane & 15;
  const bool o32 = OUT_FLAG && (f_in != 0);
#pragma unroll
  for (int ni = 0; ni < 4; ++ni) {
    const int gcol = n0 + wn * 64 + ni * 16 + ccl;
    float bvv = 0.f;
    if (HAS_BIAS)
      bvv = (f_in != 0) ? ((const float*)bias)[gcol] : bf2f(((const u16*)bias)[gcol]);
#pragma unroll
    for (int mi = 0; mi < 4; ++mi)
#pragma unroll
      for (int r = 0; r < 4; ++r) {
        const long grow = (long)(m0 + wm * 64 + mi * 16 + cr + r);
        const float val = acc[mi][ni][r] + bvv;
        const long idx = z * sC + grow * N + gcol;
        if (o32) ((float*)Cv)[idx] = val;
        else     ((u16*)Cv)[idx]   = f2bf(val);
      }
  }
}

// ---------------- row softmax fp32 -> bf16 attn, N=2048, one block/row ----------------
__global__ __launch_bounds__(256)
void softmax_rows_bf(const float* __restrict__ S, u16* __restrict__ P, int N)
{
  const float* row = S + (long)blockIdx.x * N;
  u16* prow = P + (long)blockIdx.x * N;
  const int t = threadIdx.x;
  f4v v0 = *(const f4v*)(row + t * 8);
  f4v v1 = *(const f4v*)(row + t * 8 + 4);

  float m = v0[0];
#pragma unroll
  for (int j = 1; j < 4; ++j) m = fmaxf(m, v0[j]);
#pragma unroll
  for (int j = 0; j < 4; ++j) m = fmaxf(m, v1[j]);
  for (int off = 32; off > 0; off >>= 1) m = fmaxf(m, __shfl_down(m, off, 64));

  __shared__ float redm[4], reds[4];
  if ((t & 63) == 0) redm[t >> 6] = m;
  __syncthreads();
  m = fmaxf(fmaxf(redm[0], redm[1]), fmaxf(redm[2], redm[3]));

  float s = 0.f;
#pragma unroll
  for (int j = 0; j < 4; ++j) { v0[j] = __expf(v0[j] - m); s += v0[j]; }
#pragma unroll
  for (int j = 0; j < 4; ++j) { v1[j] = __expf(v1[j] - m); s += v1[j]; }
  for (int off = 32; off > 0; off >>= 1) s += __shfl_down(s, off, 64);
  if ((t & 63) == 0) reds[t >> 6] = s;
  __syncthreads();
  s = reds[0] + reds[1] + reds[2] + reds[3];

  const float inv = 1.f / s;
  s8v o;
#pragma unroll
  for (int j = 0; j < 4; ++j) {
    o[j]     = (short)f2bf(v0[j] * inv);
    o[4 + j] = (short)f2bf(v1[j] * inv);
  }
  *(s8v*)(prow + t * 8) = o;
}

extern "C" void kernel_launch(void* const* d_in, const int* in_sizes, int n_in,
                              void* d_out, int out_size, void* d_ws, size_t ws_size,
                              hipStream_t stream)
{
  const void* query = d_in[0];
  const void* kv    = d_in[1];
  const void* Wq    = d_in[2];
  const void* bq    = d_in[3];
  const void* Wk    = d_in[4];
  const void* bk    = d_in[5];
  const void* Wv    = d_in[6];
  const void* bv    = d_in[7];
  const void* Wo    = d_in[8];
  const void* bo    = d_in[9];

  const int Bn = 4, S = 2048, D = 1024;
  const int MS = Bn * S;                       // 8192
  const size_t KBu = 1024, MBu = 1024 * 1024;
  const long nTok = (long)MS * D;

  // ---- workspace layout (~168 MB; ws proven >= 173 MB) ----
  char* ws = (char*)d_ws;
  int*  flg  = (int*)(ws);
  f16*  Qi   = (f16*)(ws + 64 * KBu);          // 16MB fp16 input tokens
  f16*  KVi  = (f16*)(ws + 64 * KBu + 16 * MBu);
  char* rW   = ws + 64 * KBu + 32 * MBu;       // 8MB: W^T
  f16*  WqT  = (f16*)(rW);
  f16*  WkT  = (f16*)(rW + 2 * MBu);
  f16*  WvT  = (f16*)(rW + 4 * MBu);
  u16*  WoT  = (u16*)(rW + 6 * MBu);
  char* rQK  = rW + 8 * MBu;                   // 32MB: Q,K fp16; later attn bf16
  f16*  Qf   = (f16*)(rQK);
  f16*  Kf   = (f16*)(rQK + 16 * MBu);
  u16*  attn = (u16*)(rQK);                    // 32MB (Q/K dead after scores)
  float* Sc  = (float*)(rQK + 32 * MBu);       // 64MB fp32 scores
  char* rV   = rQK + 96 * MBu;                 // 32MB
  u16*  Vt   = (u16*)(rV);                     // [B][D][S] bf16
  u16*  Cx   = (u16*)(rV + 16 * MBu);          // [B][S][D] bf16

  detect_dtype<<<1, 256, 0, stream>>>((const u16*)query, flg);

  convert_h<<<dim3((unsigned)(nTok / 2048), 2), 256, 0, stream>>>(
      flg, query, kv, Qi, KVi, nTok);

  dim3 tb(32, 8);
  transpose_w4<<<dim3(32, 32, 4), tb, 0, stream>>>(
      flg, Wq, Wk, Wv, Wo, WqT, WkT, WvT, WoT, D);

  // Q, K, V projections in one dispatch (V -> Vt transposed), 256^2 tiles
  gemm_proj3<<<dim3(D / 256, MS / 256, 3), 512, 0, stream>>>(
      flg, Qi, KVi, WqT, WkT, WvT, bq, bk, bv, Qf, Kf, Vt, MS, D, D, S);

  // scores (fp16, fp32 out), softmax -> bf16 attn, PV (bf16)
  gemm_sc<<<dim3(S / 256, S / 256, Bn), 512, 0, stream>>>(
      Qf, Kf, Sc, S, S, D, (long)S * D, (long)S * D, (long)S * S);
  softmax_rows_bf<<<dim3(Bn * S), 256, 0, stream>>>(Sc, attn, S);
  gemm_bf<false, false><<<dim3(D / 128, S / 256, Bn), 512, 0, stream>>>(
      flg, attn, Vt, nullptr, Cx, S, D, S, (long)S * S, (long)D * S, (long)S * D);

  // output projection -> d_out (dtype per flag)
  gemm_bf<true, true><<<dim3(D / 128, MS / 256, 1), 512, 0, stream>>>(
      flg, Cx, WoT, bo, d_out, MS, D, D, 0L, 0L, 0L);
}